// Round 6
// baseline (75.597 us; speedup 1.0000x reference)
//
#include <hip/hip_runtime.h>

#define B_DIM 32
#define O_DIM 1000
#define M_DIM 100
#define F_DIM 32
#define DS 6
#define DD 3
#define SEG 25      // o-segments per batch
#define CHUNK 40    // O_DIM / SEG
#define OSUB 10     // o-subgroups per block
#define TRIPS 4     // CHUNK / OSUB
#define PART_FLOATS ((size_t)B_DIM * SEG * M_DIM * 8)   // 640000 floats = 2.56 MB

// Fused kernel: grid = B*SEG. Each block computes one segment's partial sums;
// the last block per batch (device-scope semaphore) finishes that batch.
__global__ __launch_bounds__(256) void gat_fused(
    const float* __restrict__ raw_opes,   // [B,O,DS]
    const float* __restrict__ raw_mas,    // [B,M,DD]
    const float* __restrict__ proc_time,  // [B,O,M]
    const int*   __restrict__ adj,        // [Btot,O,M]
    const int*   __restrict__ bidx,       // [B]
    const float* __restrict__ Wsrc,       // [DS,F]
    const float* __restrict__ Wdst,       // [DD,F]
    const float* __restrict__ Wedge,      // [F]
    const float* __restrict__ attn_l,     // [F]
    const float* __restrict__ attn_r,     // [F]
    float* __restrict__ partial,          // [B,SEG,M,8]
    int*   __restrict__ cnt,              // [B], zeroed per launch
    float* __restrict__ out)              // [B,M,F]
{
    const int b   = blockIdx.x / SEG;
    const int seg = blockIdx.x % SEG;
    const int t   = threadIdx.x;
    const int o0  = seg * CHUNK;

    __shared__ float ro_s[CHUNK * DS];
    __shared__ float part_s[OSUB][M_DIM][9];   // +1 pad; reused as smd by finisher
    __shared__ int   flag_s;

    const int mg = t % 25;   // consecutive lanes -> consecutive m (coalesced)
    const int g  = t / 25;   // o-subgroup

    // Issue the hot-loop loads FIRST: 8 outstanding 16B loads/thread.
    float4 pt[TRIPS];
    int4   av[TRIPS];
    if (t < 25 * OSUB) {
        const float* ptp = proc_time + ((size_t)b * O_DIM + o0) * M_DIM + mg * 4;
        #pragma unroll
        for (int k = 0; k < TRIPS; ++k)
            pt[k] = *(const float4*)(ptp + (g + k * OSUB) * M_DIM);
        const int* adp = adj + ((size_t)bidx[b] * O_DIM + o0) * M_DIM + mg * 4;
        #pragma unroll
        for (int k = 0; k < TRIPS; ++k)
            av[k] = *(const int4*)(adp + (g + k * OSUB) * M_DIM);
    }

    // Stage this segment's raw_opes (240 floats) — overlaps with prefetch.
    const float* rop = raw_opes + ((size_t)b * O_DIM + o0) * DS;
    if (t < CHUNK * DS) ro_s[t] = rop[t];

    // Folded weights (uniform; scalar loads overlap outstanding VMEM).
    float wl[DS] = {0, 0, 0, 0, 0, 0};
    float we = 0.f;
    for (int f = 0; f < F_DIM; ++f) {
        float al = attn_l[f];
        we = fmaf(Wedge[f], al, we);
        #pragma unroll
        for (int d = 0; d < DS; ++d) wl[d] = fmaf(Wsrc[d * F_DIM + f], al, wl[d]);
    }
    float wr[DD] = {0, 0, 0};
    for (int f = 0; f < F_DIM; ++f) {
        float ar = attn_r[f];
        #pragma unroll
        for (int d = 0; d < DD; ++d) wr[d] = fmaf(Wdst[d * F_DIM + f], ar, wr[d]);
    }
    __syncthreads();

    if (t < 25 * OSUB) {
        const float* rm = raw_mas + ((size_t)b * M_DIM + mg * 4) * DD;
        float4 er;
        er.x = fmaf(rm[0], wr[0], fmaf(rm[1],  wr[1], rm[2]  * wr[2]));
        er.y = fmaf(rm[3], wr[0], fmaf(rm[4],  wr[1], rm[5]  * wr[2]));
        er.z = fmaf(rm[6], wr[0], fmaf(rm[7],  wr[1], rm[8]  * wr[2]));
        er.w = fmaf(rm[9], wr[0], fmaf(rm[10], wr[1], rm[11] * wr[2]));

        float4 den = make_float4(0, 0, 0, 0), spa = make_float4(0, 0, 0, 0);
        float4 sd[DS];
        #pragma unroll
        for (int d = 0; d < DS; ++d) sd[d] = make_float4(0, 0, 0, 0);

        #pragma unroll
        for (int k = 0; k < TRIPS; ++k) {
            const int row = g + k * OSUB;
            float ro[DS];
            #pragma unroll
            for (int d = 0; d < DS; ++d) ro[d] = ro_s[row * DS + d];
            float elr = 0.f;
            #pragma unroll
            for (int d = 0; d < DS; ++d) elr = fmaf(ro[d], wl[d], elr);

            float s0 = elr + er.x + we * pt[k].x;
            float s1 = elr + er.y + we * pt[k].y;
            float s2 = elr + er.z + we * pt[k].z;
            float s3 = elr + er.w + we * pt[k].w;
            s0 = fmaxf(s0, 0.2f * s0); s1 = fmaxf(s1, 0.2f * s1);
            s2 = fmaxf(s2, 0.2f * s2); s3 = fmaxf(s3, 0.2f * s3);
            float p0 = (av[k].x == 1) ? __expf(s0) : 0.f;
            float p1 = (av[k].y == 1) ? __expf(s1) : 0.f;
            float p2 = (av[k].z == 1) ? __expf(s2) : 0.f;
            float p3 = (av[k].w == 1) ? __expf(s3) : 0.f;
            den.x += p0; den.y += p1; den.z += p2; den.w += p3;
            spa.x = fmaf(p0, pt[k].x, spa.x); spa.y = fmaf(p1, pt[k].y, spa.y);
            spa.z = fmaf(p2, pt[k].z, spa.z); spa.w = fmaf(p3, pt[k].w, spa.w);
            #pragma unroll
            for (int d = 0; d < DS; ++d) {
                sd[d].x = fmaf(p0, ro[d], sd[d].x);
                sd[d].y = fmaf(p1, ro[d], sd[d].y);
                sd[d].z = fmaf(p2, ro[d], sd[d].z);
                sd[d].w = fmaf(p3, ro[d], sd[d].w);
            }
        }

        #pragma unroll
        for (int j = 0; j < 4; ++j) {
            const int m = mg * 4 + j;
            float* ps = part_s[g][m];
            ps[0] = j == 0 ? den.x : j == 1 ? den.y : j == 2 ? den.z : den.w;
            ps[1] = j == 0 ? spa.x : j == 1 ? spa.y : j == 2 ? spa.z : spa.w;
            #pragma unroll
            for (int d = 0; d < DS; ++d)
                ps[2 + d] = j == 0 ? sd[d].x : j == 1 ? sd[d].y : j == 2 ? sd[d].z : sd[d].w;
        }
    }
    __syncthreads();

    // Cross-group reduce -> global partial.
    if (t < 2 * M_DIM) {
        const int m = t % M_DIM, half = t / M_DIM;
        float a[4] = {0, 0, 0, 0};
        #pragma unroll
        for (int gg = 0; gg < OSUB; ++gg) {
            #pragma unroll
            for (int k = 0; k < 4; ++k) a[k] += part_s[gg][m][half * 4 + k];
        }
        *(float4*)(partial + (((size_t)b * SEG + seg) * M_DIM + m) * 8 + half * 4) =
            make_float4(a[0], a[1], a[2], a[3]);
    }
    __syncthreads();   // drains the partial stores (vmcnt 0) for all threads

    if (t == 0) {
        __threadfence();   // belt-and-braces: device-scope release of partials
        int old = __hip_atomic_fetch_add(cnt + b, 1, __ATOMIC_ACQ_REL,
                                         __HIP_MEMORY_SCOPE_AGENT);
        flag_s = (old == SEG - 1);
    }
    __syncthreads();
    if (!flag_s) return;

    // ---- Finisher: this block saw all SEG partials of batch b complete. ----
    __threadfence();   // acquire: invalidate L1/L2 so cross-XCD partials are fresh
    float (*smd)[9] = part_s[0];   // reuse LDS

    if (t < 2 * M_DIM) {
        const int m = t % M_DIM, half = t / M_DIM;
        const float* p = partial + ((size_t)b * SEG * M_DIM + m) * 8 + half * 4;
        float4 acc = make_float4(0, 0, 0, 0);
        #pragma unroll
        for (int s = 0; s < SEG; ++s) {
            float4 x = *(const float4*)(p + (size_t)s * M_DIM * 8);
            acc.x += x.x; acc.y += x.y; acc.z += x.z; acc.w += x.w;
        }
        smd[m][half * 4 + 0] = acc.x;
        smd[m][half * 4 + 1] = acc.y;
        smd[m][half * 4 + 2] = acc.z;
        smd[m][half * 4 + 3] = acc.w;
    }
    __syncthreads();

    if (t < M_DIM) {
        const float* rm = raw_mas + ((size_t)b * M_DIM + t) * DD;
        float er = fmaf(rm[0], wr[0], fmaf(rm[1], wr[1], rm[2] * wr[2]));
        float skk = 2.f * er;
        skk = fmaxf(skk, 0.2f * skk);
        float pkk = __expf(skk);
        float den = smd[t][0], spa = smd[t][1];
        float s0 = smd[t][2], s1 = smd[t][3], s2 = smd[t][4],
              s3 = smd[t][5], s4 = smd[t][6], s5 = smd[t][7];
        float inv = 1.f / (den + pkk);
        smd[t][0] = s0 * inv; smd[t][1] = s1 * inv; smd[t][2] = s2 * inv;
        smd[t][3] = s3 * inv; smd[t][4] = s4 * inv; smd[t][5] = s5 * inv;
        smd[t][6] = spa * inv;
        smd[t][7] = pkk * inv;
    }
    __syncthreads();

    for (int idx = t; idx < M_DIM * F_DIM; idx += 256) {
        const int m = idx >> 5;
        const int f = idx & 31;
        float v = smd[m][6] * Wedge[f];
        #pragma unroll
        for (int d = 0; d < DS; ++d) v = fmaf(smd[m][d], Wsrc[d * F_DIM + f], v);
        const float* rm = raw_mas + ((size_t)b * M_DIM + m) * DD;
        float fd = 0.f;
        #pragma unroll
        for (int d = 0; d < DD; ++d) fd = fmaf(rm[d], Wdst[d * F_DIM + f], fd);
        v = fmaf(fd, smd[m][7], v);
        out[((size_t)b * M_DIM + m) * F_DIM + f] = 1.f / (1.f + __expf(-v));
    }
}

extern "C" void kernel_launch(void* const* d_in, const int* in_sizes, int n_in,
                              void* d_out, int out_size, void* d_ws, size_t ws_size,
                              hipStream_t stream) {
    const float* raw_opes  = (const float*)d_in[0];
    const float* raw_mas   = (const float*)d_in[1];
    const float* proc_time = (const float*)d_in[2];
    const int*   adj       = (const int*)d_in[3];
    const int*   bidx      = (const int*)d_in[4];
    const float* Wsrc      = (const float*)d_in[5];
    const float* Wdst      = (const float*)d_in[6];
    const float* Wedge     = (const float*)d_in[7];
    const float* attn_l    = (const float*)d_in[8];
    const float* attn_r    = (const float*)d_in[9];
    float* out     = (float*)d_out;
    float* partial = (float*)d_ws;
    int*   cnt     = (int*)((char*)d_ws + PART_FLOATS * sizeof(float));

    hipMemsetAsync(cnt, 0, B_DIM * sizeof(int), stream);   // graph-legal memset node
    gat_fused<<<B_DIM * SEG, 256, 0, stream>>>(raw_opes, raw_mas, proc_time, adj, bidx,
                                               Wsrc, Wdst, Wedge, attn_l, attn_r,
                                               partial, cnt, out);
}

// Round 7
// 29.063 us; speedup vs baseline: 2.6011x; 2.6011x over previous
//
#include <hip/hip_runtime.h>

#define B_DIM 32
#define O_DIM 1000
#define M_DIM 100
#define F_DIM 32
#define DS 6
#define DD 3
#define SEG 25      // o-segments per batch
#define CHUNK 40    // O_DIM / SEG
#define OSUB 10     // o-subgroups per block
#define TRIPS 4     // CHUNK / OSUB
#define PART_FLOATS ((size_t)B_DIM * SEG * 8 * M_DIM)   // 640000 floats = 2.56 MB

// Fused split-K: grid = B*SEG. Each block computes one segment's partials and
// publishes them with device-coherent (sc1) relaxed atomic stores; the last
// block per batch (relaxed agent-scope counter) becomes the finisher.
// NO threadfence / NO acq-rel => no buffer_wbl2 L2 flushes (R6's 4x regression).
// partial layout: [B][SEG][8][M]  slot-major => 4B atomic stores/loads coalesce.
__global__ __launch_bounds__(256) void gat_fused(
    const float* __restrict__ raw_opes,   // [B,O,DS]
    const float* __restrict__ raw_mas,    // [B,M,DD]
    const float* __restrict__ proc_time,  // [B,O,M]
    const int*   __restrict__ adj,        // [Btot,O,M]
    const int*   __restrict__ bidx,       // [B]
    const float* __restrict__ Wsrc,       // [DS,F]
    const float* __restrict__ Wdst,       // [DD,F]
    const float* __restrict__ Wedge,      // [F]
    const float* __restrict__ attn_l,     // [F]
    const float* __restrict__ attn_r,     // [F]
    float* __restrict__ partial,          // [B,SEG,8,M]
    int*   __restrict__ cnt,              // [B], zeroed per launch
    float* __restrict__ out)              // [B,M,F]
{
    const int b   = blockIdx.x / SEG;
    const int seg = blockIdx.x % SEG;
    const int t   = threadIdx.x;
    const int o0  = seg * CHUNK;

    __shared__ float ro_s[CHUNK * DS];
    __shared__ float part_s[OSUB][M_DIM][9];   // +1 pad; reused as smd by finisher
    __shared__ int   flag_s;

    const int mg = t % 25;   // consecutive lanes -> consecutive m (coalesced)
    const int g  = t / 25;   // o-subgroup

    // Issue the hot-loop loads FIRST: 8 outstanding 16B loads/thread.
    float4 pt[TRIPS];
    int4   av[TRIPS];
    if (t < 25 * OSUB) {
        const float* ptp = proc_time + ((size_t)b * O_DIM + o0) * M_DIM + mg * 4;
        #pragma unroll
        for (int k = 0; k < TRIPS; ++k)
            pt[k] = *(const float4*)(ptp + (g + k * OSUB) * M_DIM);
        const int* adp = adj + ((size_t)bidx[b] * O_DIM + o0) * M_DIM + mg * 4;
        #pragma unroll
        for (int k = 0; k < TRIPS; ++k)
            av[k] = *(const int4*)(adp + (g + k * OSUB) * M_DIM);
    }

    // Stage this segment's raw_opes (240 floats) — overlaps with prefetch.
    const float* rop = raw_opes + ((size_t)b * O_DIM + o0) * DS;
    if (t < CHUNK * DS) ro_s[t] = rop[t];

    // Folded weights (uniform; scalar loads overlap outstanding VMEM).
    float wl[DS] = {0, 0, 0, 0, 0, 0};
    float we = 0.f;
    for (int f = 0; f < F_DIM; ++f) {
        float al = attn_l[f];
        we = fmaf(Wedge[f], al, we);
        #pragma unroll
        for (int d = 0; d < DS; ++d) wl[d] = fmaf(Wsrc[d * F_DIM + f], al, wl[d]);
    }
    float wr[DD] = {0, 0, 0};
    for (int f = 0; f < F_DIM; ++f) {
        float ar = attn_r[f];
        #pragma unroll
        for (int d = 0; d < DD; ++d) wr[d] = fmaf(Wdst[d * F_DIM + f], ar, wr[d]);
    }
    __syncthreads();

    if (t < 25 * OSUB) {
        const float* rm = raw_mas + ((size_t)b * M_DIM + mg * 4) * DD;
        float4 er;
        er.x = fmaf(rm[0], wr[0], fmaf(rm[1],  wr[1], rm[2]  * wr[2]));
        er.y = fmaf(rm[3], wr[0], fmaf(rm[4],  wr[1], rm[5]  * wr[2]));
        er.z = fmaf(rm[6], wr[0], fmaf(rm[7],  wr[1], rm[8]  * wr[2]));
        er.w = fmaf(rm[9], wr[0], fmaf(rm[10], wr[1], rm[11] * wr[2]));

        float4 den = make_float4(0, 0, 0, 0), spa = make_float4(0, 0, 0, 0);
        float4 sd[DS];
        #pragma unroll
        for (int d = 0; d < DS; ++d) sd[d] = make_float4(0, 0, 0, 0);

        #pragma unroll
        for (int k = 0; k < TRIPS; ++k) {
            const int row = g + k * OSUB;
            float ro[DS];
            #pragma unroll
            for (int d = 0; d < DS; ++d) ro[d] = ro_s[row * DS + d];
            float elr = 0.f;
            #pragma unroll
            for (int d = 0; d < DS; ++d) elr = fmaf(ro[d], wl[d], elr);

            float s0 = elr + er.x + we * pt[k].x;
            float s1 = elr + er.y + we * pt[k].y;
            float s2 = elr + er.z + we * pt[k].z;
            float s3 = elr + er.w + we * pt[k].w;
            s0 = fmaxf(s0, 0.2f * s0); s1 = fmaxf(s1, 0.2f * s1);
            s2 = fmaxf(s2, 0.2f * s2); s3 = fmaxf(s3, 0.2f * s3);
            float p0 = (av[k].x == 1) ? __expf(s0) : 0.f;
            float p1 = (av[k].y == 1) ? __expf(s1) : 0.f;
            float p2 = (av[k].z == 1) ? __expf(s2) : 0.f;
            float p3 = (av[k].w == 1) ? __expf(s3) : 0.f;
            den.x += p0; den.y += p1; den.z += p2; den.w += p3;
            spa.x = fmaf(p0, pt[k].x, spa.x); spa.y = fmaf(p1, pt[k].y, spa.y);
            spa.z = fmaf(p2, pt[k].z, spa.z); spa.w = fmaf(p3, pt[k].w, spa.w);
            #pragma unroll
            for (int d = 0; d < DS; ++d) {
                sd[d].x = fmaf(p0, ro[d], sd[d].x);
                sd[d].y = fmaf(p1, ro[d], sd[d].y);
                sd[d].z = fmaf(p2, ro[d], sd[d].z);
                sd[d].w = fmaf(p3, ro[d], sd[d].w);
            }
        }

        #pragma unroll
        for (int j = 0; j < 4; ++j) {
            const int m = mg * 4 + j;
            float* ps = part_s[g][m];
            ps[0] = j == 0 ? den.x : j == 1 ? den.y : j == 2 ? den.z : den.w;
            ps[1] = j == 0 ? spa.x : j == 1 ? spa.y : j == 2 ? spa.z : spa.w;
            #pragma unroll
            for (int d = 0; d < DS; ++d)
                ps[2 + d] = j == 0 ? sd[d].x : j == 1 ? sd[d].y : j == 2 ? sd[d].z : sd[d].w;
        }
    }
    __syncthreads();

    // Cross-group reduce -> device-coherent partial stores (sc1, no fence).
    if (t < 2 * M_DIM) {
        const int m = t % M_DIM, half = t / M_DIM;
        float a[4] = {0, 0, 0, 0};
        #pragma unroll
        for (int gg = 0; gg < OSUB; ++gg) {
            #pragma unroll
            for (int k = 0; k < 4; ++k) a[k] += part_s[gg][m][half * 4 + k];
        }
        float* base = partial + ((size_t)b * SEG + seg) * 8 * M_DIM + m;
        #pragma unroll
        for (int k = 0; k < 4; ++k)
            __hip_atomic_store(base + (half * 4 + k) * M_DIM, a[k],
                               __ATOMIC_RELAXED, __HIP_MEMORY_SCOPE_AGENT);
    }
    __syncthreads();   // drains vmcnt(0): sc1 stores complete at coherence point

    if (t == 0) {
        int old = __hip_atomic_fetch_add(cnt + b, 1, __ATOMIC_RELAXED,
                                         __HIP_MEMORY_SCOPE_AGENT);
        flag_s = (old == SEG - 1);
    }
    __syncthreads();
    if (!flag_s) return;

    // ---- Finisher: all SEG partials of batch b are at the coherence point. ----
    float (*smd)[9] = part_s[0];   // reuse LDS

    if (t < 2 * M_DIM) {
        const int ml = t % M_DIM, half = t / M_DIM;
        float acc[4] = {0, 0, 0, 0};
        #pragma unroll
        for (int s = 0; s < SEG; ++s) {
            const float* base = partial + ((size_t)b * SEG + s) * 8 * M_DIM + ml;
            #pragma unroll
            for (int k = 0; k < 4; ++k)
                acc[k] += __hip_atomic_load(base + (half * 4 + k) * M_DIM,
                                            __ATOMIC_RELAXED, __HIP_MEMORY_SCOPE_AGENT);
        }
        #pragma unroll
        for (int k = 0; k < 4; ++k) smd[ml][half * 4 + k] = acc[k];
    }
    __syncthreads();

    if (t < M_DIM) {
        const float* rm = raw_mas + ((size_t)b * M_DIM + t) * DD;
        float er = fmaf(rm[0], wr[0], fmaf(rm[1], wr[1], rm[2] * wr[2]));
        float skk = 2.f * er;
        skk = fmaxf(skk, 0.2f * skk);
        float pkk = __expf(skk);
        float den = smd[t][0], spa = smd[t][1];
        float s0 = smd[t][2], s1 = smd[t][3], s2 = smd[t][4],
              s3 = smd[t][5], s4 = smd[t][6], s5 = smd[t][7];
        float inv = 1.f / (den + pkk);
        smd[t][0] = s0 * inv; smd[t][1] = s1 * inv; smd[t][2] = s2 * inv;
        smd[t][3] = s3 * inv; smd[t][4] = s4 * inv; smd[t][5] = s5 * inv;
        smd[t][6] = spa * inv;
        smd[t][7] = pkk * inv;
    }
    __syncthreads();

    for (int idx = t; idx < M_DIM * F_DIM; idx += 256) {
        const int m = idx >> 5;
        const int f = idx & 31;
        float v = smd[m][6] * Wedge[f];
        #pragma unroll
        for (int d = 0; d < DS; ++d) v = fmaf(smd[m][d], Wsrc[d * F_DIM + f], v);
        const float* rm = raw_mas + ((size_t)b * M_DIM + m) * DD;
        float fd = 0.f;
        #pragma unroll
        for (int d = 0; d < DD; ++d) fd = fmaf(rm[d], Wdst[d * F_DIM + f], fd);
        v = fmaf(fd, smd[m][7], v);
        out[((size_t)b * M_DIM + m) * F_DIM + f] = 1.f / (1.f + __expf(-v));
    }
}

extern "C" void kernel_launch(void* const* d_in, const int* in_sizes, int n_in,
                              void* d_out, int out_size, void* d_ws, size_t ws_size,
                              hipStream_t stream) {
    const float* raw_opes  = (const float*)d_in[0];
    const float* raw_mas   = (const float*)d_in[1];
    const float* proc_time = (const float*)d_in[2];
    const int*   adj       = (const int*)d_in[3];
    const int*   bidx      = (const int*)d_in[4];
    const float* Wsrc      = (const float*)d_in[5];
    const float* Wdst      = (const float*)d_in[6];
    const float* Wedge     = (const float*)d_in[7];
    const float* attn_l    = (const float*)d_in[8];
    const float* attn_r    = (const float*)d_in[9];
    float* out     = (float*)d_out;
    float* partial = (float*)d_ws;
    int*   cnt     = (int*)((char*)d_ws + PART_FLOATS * sizeof(float));

    hipMemsetAsync(cnt, 0, B_DIM * sizeof(int), stream);   // graph-legal memset node
    gat_fused<<<B_DIM * SEG, 256, 0, stream>>>(raw_opes, raw_mas, proc_time, adj, bidx,
                                               Wsrc, Wdst, Wedge, attn_l, attn_r,
                                               partial, cnt, out);
}

// Round 8
// 17.109 us; speedup vs baseline: 4.4187x; 1.6988x over previous
//
#include <hip/hip_runtime.h>

#define B_DIM 32
#define O_DIM 1000
#define M_DIM 100
#define F_DIM 32
#define DS 6
#define DD 3
#define SEG 25      // o-segments per batch
#define CHUNK 40    // O_DIM / SEG
#define OSUB 10     // o-subgroups per block
#define TRIPS 4     // CHUNK / OSUB
#define MT 25       // m-tile per gat_final block

// Kernel 1: per (batch, o-segment) block computes partial softmax sums per m-column.
// partial layout: [B][SEG][M][8]  (0=denom, 1=sum p*pt, 2..7=sum p*raw_opes[o,d])
__global__ __launch_bounds__(256) void gat_partial(
    const float* __restrict__ raw_opes,   // [B,O,DS]
    const float* __restrict__ raw_mas,    // [B,M,DD]
    const float* __restrict__ proc_time,  // [B,O,M]
    const int*   __restrict__ adj,        // [Btot,O,M]
    const int*   __restrict__ bidx,       // [B]
    const float* __restrict__ Wsrc,       // [DS,F]
    const float* __restrict__ Wdst,       // [DD,F]
    const float* __restrict__ Wedge,      // [F]
    const float* __restrict__ attn_l,     // [F]
    const float* __restrict__ attn_r,     // [F]
    float* __restrict__ partial)
{
    const int b   = blockIdx.x / SEG;
    const int seg = blockIdx.x % SEG;
    const int t   = threadIdx.x;
    const int o0  = seg * CHUNK;

    __shared__ float ro_s[CHUNK * DS];
    __shared__ float part_s[OSUB][M_DIM][9];   // +1 pad
    __shared__ float wfold[10];                // wl[0..5], we, wr[0..2]

    const int mg = t % 25;   // consecutive lanes -> consecutive m (coalesced)
    const int g  = t / 25;   // o-subgroup

    // Issue the hot-loop loads FIRST: 8 outstanding 16B loads/thread.
    float4 pt[TRIPS];
    int4   av[TRIPS];
    if (t < 25 * OSUB) {
        const float* ptp = proc_time + ((size_t)b * O_DIM + o0) * M_DIM + mg * 4;
        #pragma unroll
        for (int k = 0; k < TRIPS; ++k)
            pt[k] = *(const float4*)(ptp + (g + k * OSUB) * M_DIM);
        const int* adp = adj + ((size_t)bidx[b] * O_DIM + o0) * M_DIM + mg * 4;
        #pragma unroll
        for (int k = 0; k < TRIPS; ++k)
            av[k] = *(const int4*)(adp + (g + k * OSUB) * M_DIM);
    }

    // Stage this segment's raw_opes (240 floats).
    const float* rop = raw_opes + ((size_t)b * O_DIM + o0) * DS;
    if (t < CHUNK * DS) ro_s[t] = rop[t];

    // Wave-parallel weight fold (wave 3): lane f loads one column of every
    // weight vector (coalesced, independent), butterfly-reduces over 32 lanes.
    // Replaces the per-thread 32-iteration serial fold (R5's hidden latency chain).
    if (t >= 192) {
        const int l = t - 192;
        const int f = l & 31;
        float al = attn_l[f], ar = attn_r[f];
        float p[10];
        #pragma unroll
        for (int d = 0; d < DS; ++d) p[d] = Wsrc[d * F_DIM + f] * al;
        p[6] = Wedge[f] * al;
        #pragma unroll
        for (int d = 0; d < DD; ++d) p[7 + d] = Wdst[d * F_DIM + f] * ar;
        #pragma unroll
        for (int s = 1; s < 32; s <<= 1) {
            #pragma unroll
            for (int k = 0; k < 10; ++k) p[k] += __shfl_xor(p[k], s);
        }
        if (l == 0) {
            #pragma unroll
            for (int k = 0; k < 10; ++k) wfold[k] = p[k];
        }
    }
    __syncthreads();

    if (t < 25 * OSUB) {
        float wl[DS], wr[DD], we;
        #pragma unroll
        for (int d = 0; d < DS; ++d) wl[d] = wfold[d];
        we = wfold[6];
        #pragma unroll
        for (int d = 0; d < DD; ++d) wr[d] = wfold[7 + d];

        const float* rm = raw_mas + ((size_t)b * M_DIM + mg * 4) * DD;
        float4 er;
        er.x = fmaf(rm[0], wr[0], fmaf(rm[1],  wr[1], rm[2]  * wr[2]));
        er.y = fmaf(rm[3], wr[0], fmaf(rm[4],  wr[1], rm[5]  * wr[2]));
        er.z = fmaf(rm[6], wr[0], fmaf(rm[7],  wr[1], rm[8]  * wr[2]));
        er.w = fmaf(rm[9], wr[0], fmaf(rm[10], wr[1], rm[11] * wr[2]));

        float4 den = make_float4(0, 0, 0, 0), spa = make_float4(0, 0, 0, 0);
        float4 sd[DS];
        #pragma unroll
        for (int d = 0; d < DS; ++d) sd[d] = make_float4(0, 0, 0, 0);

        #pragma unroll
        for (int k = 0; k < TRIPS; ++k) {
            const int row = g + k * OSUB;
            float ro[DS];
            #pragma unroll
            for (int d = 0; d < DS; ++d) ro[d] = ro_s[row * DS + d];
            float elr = 0.f;
            #pragma unroll
            for (int d = 0; d < DS; ++d) elr = fmaf(ro[d], wl[d], elr);

            float s0 = elr + er.x + we * pt[k].x;
            float s1 = elr + er.y + we * pt[k].y;
            float s2 = elr + er.z + we * pt[k].z;
            float s3 = elr + er.w + we * pt[k].w;
            s0 = fmaxf(s0, 0.2f * s0); s1 = fmaxf(s1, 0.2f * s1);
            s2 = fmaxf(s2, 0.2f * s2); s3 = fmaxf(s3, 0.2f * s3);
            float p0 = (av[k].x == 1) ? __expf(s0) : 0.f;
            float p1 = (av[k].y == 1) ? __expf(s1) : 0.f;
            float p2 = (av[k].z == 1) ? __expf(s2) : 0.f;
            float p3 = (av[k].w == 1) ? __expf(s3) : 0.f;
            den.x += p0; den.y += p1; den.z += p2; den.w += p3;
            spa.x = fmaf(p0, pt[k].x, spa.x); spa.y = fmaf(p1, pt[k].y, spa.y);
            spa.z = fmaf(p2, pt[k].z, spa.z); spa.w = fmaf(p3, pt[k].w, spa.w);
            #pragma unroll
            for (int d = 0; d < DS; ++d) {
                sd[d].x = fmaf(p0, ro[d], sd[d].x);
                sd[d].y = fmaf(p1, ro[d], sd[d].y);
                sd[d].z = fmaf(p2, ro[d], sd[d].z);
                sd[d].w = fmaf(p3, ro[d], sd[d].w);
            }
        }

        #pragma unroll
        for (int j = 0; j < 4; ++j) {
            const int m = mg * 4 + j;
            float* ps = part_s[g][m];
            ps[0] = j == 0 ? den.x : j == 1 ? den.y : j == 2 ? den.z : den.w;
            ps[1] = j == 0 ? spa.x : j == 1 ? spa.y : j == 2 ? spa.z : spa.w;
            #pragma unroll
            for (int d = 0; d < DS; ++d)
                ps[2 + d] = j == 0 ? sd[d].x : j == 1 ? sd[d].y : j == 2 ? sd[d].z : sd[d].w;
        }
    }
    __syncthreads();

    // Reduce over OSUB groups and write [m][8] partials.
    if (t < 2 * M_DIM) {
        const int m = t % M_DIM, half = t / M_DIM;
        float a[4] = {0, 0, 0, 0};
        #pragma unroll
        for (int gg = 0; gg < OSUB; ++gg) {
            #pragma unroll
            for (int k = 0; k < 4; ++k) a[k] += part_s[gg][m][half * 4 + k];
        }
        *(float4*)(partial + (((size_t)b * SEG + seg) * M_DIM + m) * 8 + half * 4) =
            make_float4(a[0], a[1], a[2], a[3]);
    }
}

// Kernel 2: reduce segments, normalize, emit sigmoid output. Grid = B*4.
__global__ __launch_bounds__(256) void gat_final(
    const float* __restrict__ raw_mas,    // [B,M,DD]
    const float* __restrict__ Wsrc,       // [DS,F]
    const float* __restrict__ Wdst,       // [DD,F]
    const float* __restrict__ Wedge,      // [F]
    const float* __restrict__ attn_r,     // [F]
    const float* __restrict__ partial,
    float* __restrict__ out)              // [B,M,F]
{
    const int b  = blockIdx.x >> 2;
    const int m0 = (blockIdx.x & 3) * MT;
    const int t  = threadIdx.x;

    __shared__ float smd[MT][9];
    __shared__ float wr_s[DD];

    // Wave-parallel attn_r fold (wave 3, overlaps the reduce phase issue).
    if (t >= 192) {
        const int l = t - 192;
        const int f = l & 31;
        float ar = attn_r[f];
        float p[DD];
        #pragma unroll
        for (int d = 0; d < DD; ++d) p[d] = Wdst[d * F_DIM + f] * ar;
        #pragma unroll
        for (int s = 1; s < 32; s <<= 1) {
            #pragma unroll
            for (int d = 0; d < DD; ++d) p[d] += __shfl_xor(p[d], s);
        }
        if (l == 0) {
            #pragma unroll
            for (int d = 0; d < DD; ++d) wr_s[d] = p[d];
        }
    }

    if (t < MT * 8) {
        const int ml = t % MT;
        const int k  = t / MT;
        const float* p = partial + (((size_t)b * SEG) * M_DIM + m0 + ml) * 8 + k;
        float acc = 0.f;
        #pragma unroll
        for (int s = 0; s < SEG; ++s) acc += p[(size_t)s * M_DIM * 8];
        smd[ml][k] = acc;
    }
    __syncthreads();

    if (t < MT) {
        const float* rm = raw_mas + ((size_t)b * M_DIM + m0 + t) * DD;
        float er = fmaf(rm[0], wr_s[0], fmaf(rm[1], wr_s[1], rm[2] * wr_s[2]));
        float skk = 2.f * er;
        skk = fmaxf(skk, 0.2f * skk);
        float pkk = __expf(skk);
        float den = smd[t][0], spa = smd[t][1];
        float s0 = smd[t][2], s1 = smd[t][3], s2 = smd[t][4],
              s3 = smd[t][5], s4 = smd[t][6], s5 = smd[t][7];
        float inv = 1.f / (den + pkk);
        smd[t][0] = s0 * inv; smd[t][1] = s1 * inv; smd[t][2] = s2 * inv;
        smd[t][3] = s3 * inv; smd[t][4] = s4 * inv; smd[t][5] = s5 * inv;
        smd[t][6] = spa * inv;
        smd[t][7] = pkk * inv;
    }
    __syncthreads();

    for (int idx = t; idx < MT * F_DIM; idx += 256) {
        const int ml = idx >> 5;
        const int f  = idx & 31;
        float v = smd[ml][6] * Wedge[f];
        #pragma unroll
        for (int d = 0; d < DS; ++d) v = fmaf(smd[ml][d], Wsrc[d * F_DIM + f], v);
        const float* rm = raw_mas + ((size_t)b * M_DIM + m0 + ml) * DD;
        float fd = 0.f;
        #pragma unroll
        for (int d = 0; d < DD; ++d) fd = fmaf(rm[d], Wdst[d * F_DIM + f], fd);
        v = fmaf(fd, smd[ml][7], v);
        out[((size_t)b * M_DIM + m0 + ml) * F_DIM + f] = 1.f / (1.f + __expf(-v));
    }
}

extern "C" void kernel_launch(void* const* d_in, const int* in_sizes, int n_in,
                              void* d_out, int out_size, void* d_ws, size_t ws_size,
                              hipStream_t stream) {
    const float* raw_opes  = (const float*)d_in[0];
    const float* raw_mas   = (const float*)d_in[1];
    const float* proc_time = (const float*)d_in[2];
    const int*   adj       = (const int*)d_in[3];
    const int*   bidx      = (const int*)d_in[4];
    const float* Wsrc      = (const float*)d_in[5];
    const float* Wdst      = (const float*)d_in[6];
    const float* Wedge     = (const float*)d_in[7];
    const float* attn_l    = (const float*)d_in[8];
    const float* attn_r    = (const float*)d_in[9];
    float* out     = (float*)d_out;
    float* partial = (float*)d_ws;   // 32*25*100*8*4 = 2.56 MB

    gat_partial<<<B_DIM * SEG, 256, 0, stream>>>(raw_opes, raw_mas, proc_time, adj, bidx,
                                                 Wsrc, Wdst, Wedge, attn_l, attn_r, partial);
    gat_final<<<B_DIM * 4, 256, 0, stream>>>(raw_mas, Wsrc, Wdst, Wedge, attn_r, partial, out);
}